// Round 9
// baseline (236.236 us; speedup 1.0000x reference)
//
#include <hip/hip_runtime.h>
#include <hip/hip_bf16.h>
#include <math.h>

#define SEQ 4096
#define DM  768
#define NH  12
#define HD  64
#define PER ((size_t)NH * SEQ * HD)       // 3,145,728
#define XN  ((size_t)SEQ * DM)
#define WN  ((size_t)DM * DM)

typedef __attribute__((ext_vector_type(8))) short bf16x8;   // MFMA A/B frag
typedef __attribute__((ext_vector_type(4))) short s16x4;
typedef __attribute__((ext_vector_type(4))) float f32x4;    // MFMA C/D frag

#define MFMA(a, b, c) __builtin_amdgcn_mfma_f32_16x16x32_bf16((a), (b), (c), 0, 0, 0)

#if __has_builtin(__builtin_amdgcn_exp2f)
#define EXP2(x) __builtin_amdgcn_exp2f(x)
#else
#define EXP2(x) exp2f(x)
#endif

// XOR-swizzled 64-wide bf16 LDS tile, 16B blocks (conflict-free b128).
#define SWZ(row, blk) (((row) << 6) + ((((blk) ^ ((row) & 7))) << 3))

// fast RTNE fp32->bf16 (finite values only)
__device__ __forceinline__ unsigned short f2b(float f) {
    unsigned int u = __float_as_uint(f);
    u += 0x7FFFu + ((u >> 16) & 1u);
    return (unsigned short)(u >> 16);
}

// ---------------------------------------------------------------------------
// Prep: ONE kernel converts x + 4 weights fp32->bf16 and fills the RoPE table.
// ---------------------------------------------------------------------------
__global__ __launch_bounds__(256) void prep_kernel(
    const float* __restrict__ x,  const float* __restrict__ wq,
    const float* __restrict__ wk, const float* __restrict__ wv,
    const float* __restrict__ wo,
    unsigned short* __restrict__ dstbase, float2* __restrict__ rope)
{
    const float* srcs[5] = {x, wq, wk, wv, wo};
    const size_t n4s[5]  = {XN / 4, WN / 4, WN / 4, WN / 4, WN / 4};
    unsigned short* d = dstbase;
    for (int rg = 0; rg < 5; ++rg) {
        const float4* s4 = (const float4*)srcs[rg];
        s16x4* d4 = (s16x4*)d;
        for (size_t i = (size_t)blockIdx.x * 256 + threadIdx.x; i < n4s[rg];
             i += (size_t)gridDim.x * 256) {
            const float4 v = s4[i];
            s16x4 p;
            p.x = (short)f2b(v.x); p.y = (short)f2b(v.y);
            p.z = (short)f2b(v.z); p.w = (short)f2b(v.w);
            d4[i] = p;
        }
        d += n4s[rg] * 4;
    }
    for (int g = blockIdx.x * 256 + threadIdx.x; g < 131072; g += gridDim.x * 256) {
        const int row = g >> 5, fi = g & 31;
        const float invf = expf(-(float)fi * 0.28782313662425576f);
        float sn, cs;
        sincosf((float)row * invf, &sn, &cs);
        rope[row * 32 + fi] = make_float2(cs, sn);
    }
}

// ---------------------------------------------------------------------------
// K1: FUSED QKV projection — verified round 5, ONE change: Vo stored with
// per-32-key-group interleave (col 2m <-> key m, col 2m+1 <-> key m+16) to
// match attn's new packed P-strip layout (the contraction axis of PV is
// permuted identically on both operands -> exact).
// ---------------------------------------------------------------------------
__global__ __launch_bounds__(256) void qkv_mfma(
    const float* __restrict__ x,  const unsigned short* __restrict__ xb,
    const float* __restrict__ Wq, const float* __restrict__ Wk, const float* __restrict__ Wv,
    const unsigned short* __restrict__ Wqb, const unsigned short* __restrict__ Wkb,
    const unsigned short* __restrict__ Wvb,
    const float2* __restrict__ rope,
    unsigned short* __restrict__ Qo, unsigned short* __restrict__ Ko,
    unsigned short* __restrict__ Vo, int fast)
{
    __shared__ __align__(16) unsigned short Xs[2][4096];
    __shared__ __align__(16) unsigned short Ws[2][3][4096];
    __shared__ unsigned short VL[64 * 66];

    const int t    = threadIdx.x;
    const int w    = t >> 6;
    const int lane = t & 63;
    const int quad = lane >> 4;
    const int l16  = lane & 15;

    // XCD-clustered remap (bijective, 768 = 8 * 96)
    const int gid = blockIdx.y * 64 + blockIdx.x;
    const int Wl  = (gid & 7) * 96 + (gid >> 3);
    const int h   = Wl % 12;
    const int s0  = (Wl / 12) * 64;
    const int n0  = h * 64;

    const unsigned short* Wbs[3] = {Wqb, Wkb, Wvb};
    const float*          Wfs[3] = {Wq, Wk, Wv};

    const int rowb = 32 * (w >> 1);   // wave's row base within tile
    const int colb = 32 * (w & 1);    // wave's col base within each region

    f32x4 acc[3][2][2];
    #pragma unroll
    for (int rg = 0; rg < 3; ++rg)
        #pragma unroll
        for (int mi = 0; mi < 2; ++mi)
            #pragma unroll
            for (int ni = 0; ni < 2; ++ni) acc[rg][mi][ni] = (f32x4){0,0,0,0};

    const int prow = t >> 3, pblk = t & 7;

    bf16x8 xr0, xr1, wr0[3], wr1[3];
    if (fast) {
        xr0 = *(const bf16x8*)&xb[(size_t)(s0 + prow) * DM + pblk * 8];
        xr1 = *(const bf16x8*)&xb[(size_t)(s0 + prow + 32) * DM + pblk * 8];
        #pragma unroll
        for (int rg = 0; rg < 3; ++rg) {
            wr0[rg] = *(const bf16x8*)&Wbs[rg][(size_t)(n0 + prow) * DM + pblk * 8];
            wr1[rg] = *(const bf16x8*)&Wbs[rg][(size_t)(n0 + prow + 32) * DM + pblk * 8];
        }
        *(bf16x8*)&Xs[0][SWZ(prow, pblk)]      = xr0;
        *(bf16x8*)&Xs[0][SWZ(prow + 32, pblk)] = xr1;
        #pragma unroll
        for (int rg = 0; rg < 3; ++rg) {
            *(bf16x8*)&Ws[0][rg][SWZ(prow, pblk)]      = wr0[rg];
            *(bf16x8*)&Ws[0][rg][SWZ(prow + 32, pblk)] = wr1[rg];
        }
    } else {
        for (int e = t; e < 1024; e += 256) {
            const int row = e >> 4, c4 = e & 15;
            const int off = SWZ(row, c4 >> 1) + (c4 & 1) * 4;
            const float4 xv = *(const float4*)&x[(size_t)(s0 + row) * DM + c4 * 4];
            s16x4 px; px.x = (short)f2b(xv.x); px.y = (short)f2b(xv.y);
            px.z = (short)f2b(xv.z); px.w = (short)f2b(xv.w);
            *(s16x4*)&Xs[0][off] = px;
            #pragma unroll
            for (int rg = 0; rg < 3; ++rg) {
                const float4 wv = *(const float4*)&Wfs[rg][(size_t)(n0 + row) * DM + c4 * 4];
                s16x4 pw; pw.x = (short)f2b(wv.x); pw.y = (short)f2b(wv.y);
                pw.z = (short)f2b(wv.z); pw.w = (short)f2b(wv.w);
                *(s16x4*)&Ws[0][rg][off] = pw;
            }
        }
    }
    __syncthreads();

    for (int kt = 0; kt < 12; ++kt) {
        const unsigned short* Xb = Xs[kt & 1];
        if (fast && kt < 11) {
            const int k0 = (kt + 1) * 64;
            xr0 = *(const bf16x8*)&xb[(size_t)(s0 + prow) * DM + k0 + pblk * 8];
            xr1 = *(const bf16x8*)&xb[(size_t)(s0 + prow + 32) * DM + k0 + pblk * 8];
            #pragma unroll
            for (int rg = 0; rg < 3; ++rg) {
                wr0[rg] = *(const bf16x8*)&Wbs[rg][(size_t)(n0 + prow) * DM + k0 + pblk * 8];
                wr1[rg] = *(const bf16x8*)&Wbs[rg][(size_t)(n0 + prow + 32) * DM + k0 + pblk * 8];
            }
        }
        bf16x8 a[2][2];
        #pragma unroll
        for (int mi = 0; mi < 2; ++mi)
            #pragma unroll
            for (int hh = 0; hh < 2; ++hh)
                a[mi][hh] = *(const bf16x8*)&Xb[SWZ(rowb + 16 * mi + l16, 4 * hh + quad)];
        #pragma unroll
        for (int rg = 0; rg < 3; ++rg) {
            const unsigned short* Wbt = Ws[kt & 1][rg];
            #pragma unroll
            for (int ni = 0; ni < 2; ++ni) {
                const bf16x8 b0 = *(const bf16x8*)&Wbt[SWZ(colb + 16 * ni + l16, quad)];
                const bf16x8 b1 = *(const bf16x8*)&Wbt[SWZ(colb + 16 * ni + l16, 4 + quad)];
                #pragma unroll
                for (int mi = 0; mi < 2; ++mi) {
                    acc[rg][mi][ni] = MFMA(a[mi][0], b0, acc[rg][mi][ni]);
                    acc[rg][mi][ni] = MFMA(a[mi][1], b1, acc[rg][mi][ni]);
                }
            }
        }
        if (kt < 11) {
            const int nb = (kt + 1) & 1;
            if (fast) {
                *(bf16x8*)&Xs[nb][SWZ(prow, pblk)]      = xr0;
                *(bf16x8*)&Xs[nb][SWZ(prow + 32, pblk)] = xr1;
                #pragma unroll
                for (int rg = 0; rg < 3; ++rg) {
                    *(bf16x8*)&Ws[nb][rg][SWZ(prow, pblk)]      = wr0[rg];
                    *(bf16x8*)&Ws[nb][rg][SWZ(prow + 32, pblk)] = wr1[rg];
                }
            } else {
                const int k0 = (kt + 1) * 64;
                for (int e = t; e < 1024; e += 256) {
                    const int row = e >> 4, c4 = e & 15;
                    const int off = SWZ(row, c4 >> 1) + (c4 & 1) * 4;
                    const float4 xv = *(const float4*)&x[(size_t)(s0 + row) * DM + k0 + c4 * 4];
                    s16x4 px; px.x = (short)f2b(xv.x); px.y = (short)f2b(xv.y);
                    px.z = (short)f2b(xv.z); px.w = (short)f2b(xv.w);
                    *(s16x4*)&Xs[nb][off] = px;
                    #pragma unroll
                    for (int rg = 0; rg < 3; ++rg) {
                        const float4 wv = *(const float4*)&Wfs[rg][(size_t)(n0 + row) * DM + k0 + c4 * 4];
                        s16x4 pw; pw.x = (short)f2b(wv.x); pw.y = (short)f2b(wv.y);
                        pw.z = (short)f2b(wv.z); pw.w = (short)f2b(wv.w);
                        *(s16x4*)&Ws[nb][rg][off] = pw;
                    }
                }
            }
        }
        __syncthreads();
    }

    const size_t headoff = (size_t)h * SEQ * HD;
    // ---- Q and K epilogue: RoPE + store ----
    #pragma unroll
    for (int rg = 0; rg < 2; ++rg) {
        unsigned short* dst = (rg == 0) ? Qo : Ko;
        const float qsc = (rg == 0) ? 0.18033688011112042f : 1.0f;   // 0.125*log2e
        #pragma unroll
        for (int mi = 0; mi < 2; ++mi)
            #pragma unroll
            for (int ni = 0; ni < 2; ++ni)
                #pragma unroll
                for (int r = 0; r < 4; ++r) {
                    const int srow = s0 + rowb + 16 * mi + quad * 4 + r;
                    const int d  = colb + 16 * ni + l16;
                    const int fi = d >> 1;
                    const float own = acc[rg][mi][ni][r] * qsc;
                    const float oth = __shfl_xor(own, 1);
                    float cs, sn;
                    if (fast) {
                        const float2 t2 = rope[srow * 32 + fi];
                        cs = t2.x; sn = t2.y;
                    } else {
                        const float invf = expf(-(float)fi * 0.28782313662425576f);
                        sincosf((float)srow * invf, &sn, &cs);
                    }
                    const float val = (d & 1) ? (oth * sn + own * cs)
                                              : (own * cs - oth * sn);
                    dst[headoff + (size_t)srow * HD + ((d & 1) ? 32 : 0) + fi] = f2b(val);
                }
    }
    // ---- V epilogue: transpose via LDS, store [h][64][seq] with per-32-key
    // group interleave: col 32g+2m <- key 32g+m, col 32g+2m+1 <- key 32g+m+16.
    #pragma unroll
    for (int mi = 0; mi < 2; ++mi)
        #pragma unroll
        for (int ni = 0; ni < 2; ++ni)
            #pragma unroll
            for (int r = 0; r < 4; ++r)
                VL[(colb + 16 * ni + l16) * 66 + rowb + 16 * mi + quad * 4 + r] =
                    f2b(acc[2][mi][ni][r]);
    __syncthreads();
    for (int e = t; e < 2048; e += 256) {
        const int d = e >> 5, sp = e & 31;
        const int g = sp >> 4, m = sp & 15;
        const unsigned int v = (unsigned int)VL[d * 66 + 32 * g + m] |
                               ((unsigned int)VL[d * 66 + 32 * g + m + 16] << 16);
        *(unsigned int*)&Vo[headoff + (size_t)d * SEQ + s0 + 32 * g + 2 * m] = v;
    }
}

// ---------------------------------------------------------------------------
// K2: causal flash attention, round 9. r7 base (direct K/V frag loads, zero
// main-loop barriers) with three changes:
//  (1) aQ loaded directly from global (drop Qst staging + 2 barriers, -16KB);
//  (2) packed P-strip: interleaved key order, one v_cvt_pk_bf16_f32 + one
//      ds_write_b32 per (s0,s1) pair (was 2 f2b chains + 2 ds_write_b16);
//      V stored with matching interleave by qkv -> PV contraction exact;
//  (3) epilogue serialized through ONE ACC buffer -> LDS 21,504B total
//      (strips 20480 + Lx 1024; ACC overlays strips), raising the LDS
//      residency ceiling to 7 blocks/CU (VGPR now caps at 4).
// ---------------------------------------------------------------------------
__global__ __launch_bounds__(256, 2) void attn_mfma(
    const unsigned short* __restrict__ Q,    // [h][seq][64], pre-scaled
    const unsigned short* __restrict__ K,    // [h][seq][64]
    const unsigned short* __restrict__ V,    // [h][64][seq] (transposed, interleaved)
    unsigned short* __restrict__ O,          // [4096][768]
    float* __restrict__ Part)                // [384][2][4160] fp32 partials
{
    // Ps strips [0,20480); Lx [20480,21504); ACC overlays Ps[0,18432).
    __shared__ __align__(16) unsigned char SM[21504];
    unsigned short* Ps = (unsigned short*)SM;
    float* ACC = (float*)SM;
    float* Lx  = (float*)(SM + 20480);

    // ---- XCD-clustered (head-major) block remap ----
    int h, xx;
    if (gridDim.x == 96) {
        const int gid = blockIdx.y * 96 + blockIdx.x;      // 0..1151
        const int Wl  = (gid & 7) * 144 + (gid >> 3);      // bijective
        h  = Wl / 96;
        xx = Wl - h * 96;
    } else {
        const int gid = blockIdx.y * 64 + blockIdx.x;      // 0..767
        const int Wl  = (gid & 7) * 96 + (gid >> 3);
        h  = Wl >> 6;
        xx = Wl & 63;
    }

    int i, kstart, nch, domask, partial, pslice;
    if (gridDim.x == 96) {
        if (xx < 64) {
            i = 63 - xx; kstart = 0;
            const int full = ((i * 64 + 63) >> 7) + 1;
            nch = full < 16 ? full : 16;
            domask  = (i <= 31);
            partial = (i >= 32); pslice = 0;
        } else {
            i = 127 - xx; kstart = 2048;
            nch = ((i * 64 + 63 - 2048) >> 7) + 1;
            domask = 1; partial = 1; pslice = 1;
        }
    } else {
        i = 63 - xx; kstart = 0;
        nch = ((i * 64 + 63) >> 7) + 1;
        domask = 1; partial = 0; pslice = 0;
    }
    const int q0 = i * 64;

    const int t    = threadIdx.x;
    const int w    = t >> 6;
    const int lane = t & 63;
    const int quad = lane >> 4;
    const int l16  = lane & 15;
    const size_t headoff = (size_t)h * SEQ * HD;
    const unsigned short* Kg = K + headoff;
    const unsigned short* Vg = V + headoff;

    // ---- Q fragments directly from global (L2-hit; once per block) ----
    bf16x8 aQ[4][2];
    #pragma unroll
    for (int qt = 0; qt < 4; ++qt)
        #pragma unroll
        for (int hh = 0; hh < 2; ++hh)
            aQ[qt][hh] = *(const bf16x8*)
                &Q[headoff + (size_t)(q0 + 16 * qt + l16) * HD + (4 * hh + quad) * 8];

    // ---- prologue: K fragments for chunk 0 (this wave's 32 keys) ----
    bf16x8 kf00, kf01, kf10, kf11;
    {
        const size_t kr = (size_t)(kstart + 32 * w + l16) * HD + quad * 8;
        kf00 = *(const bf16x8*)&Kg[kr];
        kf01 = *(const bf16x8*)&Kg[kr + 32];
        kf10 = *(const bf16x8*)&Kg[kr + 16 * HD];
        kf11 = *(const bf16x8*)&Kg[kr + 16 * HD + 32];
    }

    bf16x8 ones;
    #pragma unroll
    for (int ii = 0; ii < 8; ++ii) ones[ii] = (short)0x3F80;

    f32x4 oT[4][4];
    #pragma unroll
    for (int dt = 0; dt < 4; ++dt)
        #pragma unroll
        for (int qt = 0; qt < 4; ++qt) oT[dt][qt] = (f32x4){0,0,0,0};
    f32x4 lT[4] = {{0,0,0,0},{0,0,0,0},{0,0,0,0},{0,0,0,0}};

    unsigned short* usp = Ps + w * 2560;

    for (int c = 0; c < nch; ++c) {
        const int k0 = kstart + c * 128;
        const int last = (c == nch - 1);

        // ---- V frags for THIS chunk (consumed at PV, covered by QK phase) --
        const size_t vr = (size_t)l16 * SEQ + k0 + 32 * w + quad * 8;
        const bf16x8 vf0 = *(const bf16x8*)&Vg[vr];
        const bf16x8 vf1 = *(const bf16x8*)&Vg[vr + 16 * SEQ];
        const bf16x8 vf2 = *(const bf16x8*)&Vg[vr + 32 * SEQ];
        const bf16x8 vf3 = *(const bf16x8*)&Vg[vr + 48 * SEQ];

        // ---- qt-major QK + mask + exp2 + packed P store ----
        #pragma unroll
        for (int qt = 0; qt < 4; ++qt) {
            f32x4 s0 = (f32x4){0,0,0,0}, s1 = (f32x4){0,0,0,0};
            s0 = MFMA(aQ[qt][0], kf00, s0);
            s0 = MFMA(aQ[qt][1], kf01, s0);
            s1 = MFMA(aQ[qt][0], kf10, s1);
            s1 = MFMA(aQ[qt][1], kf11, s1);
            if (domask && last) {
                const int key0 = k0 + 32 * w + l16;
                #pragma unroll
                for (int r = 0; r < 4; ++r) {
                    const int qrow = q0 + 16 * qt + 4 * quad + r;
                    if (key0 > qrow)      s0[r] = -1e30f;
                    if (key0 + 16 > qrow) s1[r] = -1e30f;
                }
            }
            #pragma unroll
            for (int r = 0; r < 4; ++r) {
                const float e0 = EXP2(s0[r]), e1 = EXP2(s1[r]);
                unsigned int pk;
                asm("v_cvt_pk_bf16_f32 %0, %1, %2" : "=v"(pk) : "v"(e0), "v"(e1));
                const int row_ = (16 * qt + 4 * quad + r) * 40;
                *(unsigned int*)&usp[row_ + 2 * l16] = pk;
            }
        }

        // ---- prefetch next chunk's K frags (consumed next iter; PV covers) --
        if (c + 1 < nch) {
            const size_t kr = (size_t)(k0 + 128 + 32 * w + l16) * HD + quad * 8;
            kf00 = *(const bf16x8*)&Kg[kr];
            kf01 = *(const bf16x8*)&Kg[kr + 32];
            kf10 = *(const bf16x8*)&Kg[kr + 16 * HD];
            kf11 = *(const bf16x8*)&Kg[kr + 16 * HD + 32];
        }

        asm volatile("s_waitcnt lgkmcnt(0)" ::: "memory");

        // ---- PV + row-sum (wave-private strip; no barrier) ----
        __builtin_amdgcn_s_setprio(1);
        #pragma unroll
        for (int qt = 0; qt < 4; ++qt) {
            const bf16x8 bP = *(const bf16x8*)&usp[(16 * qt + l16) * 40 + quad * 8];
            lT[qt] = MFMA(ones, bP, lT[qt]);
            oT[0][qt] = MFMA(vf0, bP, oT[0][qt]);
            oT[1][qt] = MFMA(vf1, bP, oT[1][qt]);
            oT[2][qt] = MFMA(vf2, bP, oT[2][qt]);
            oT[3][qt] = MFMA(vf3, bP, oT[3][qt]);
        }
        __builtin_amdgcn_s_setprio(0);
    }

    // ---- cross-wave reduction: serialized through ONE ACC buffer ----
    __syncthreads();                       // strips dead from here
    if (w != 0 && quad == 0) {
        #pragma unroll
        for (int qt = 0; qt < 4; ++qt)
            Lx[w * 64 + 16 * qt + l16] = lT[qt][0];
    }
    #pragma unroll
    for (int s = 1; s < 4; ++s) {
        if (w == s) {
            #pragma unroll
            for (int dt = 0; dt < 4; ++dt)
                #pragma unroll
                for (int qt = 0; qt < 4; ++qt)
                    *(f32x4*)&ACC[(16 * qt + l16) * 72 + 16 * dt + 4 * quad] = oT[dt][qt];
        }
        __syncthreads();
        if (w == 0) {
            #pragma unroll
            for (int dt = 0; dt < 4; ++dt)
                #pragma unroll
                for (int qt = 0; qt < 4; ++qt)
                    oT[dt][qt] += *(const f32x4*)&ACC[(16 * qt + l16) * 72 + 16 * dt + 4 * quad];
        }
        __syncthreads();
    }
    if (w == 0) {
        float ls[4];
        #pragma unroll
        for (int qt = 0; qt < 4; ++qt)
            ls[qt] = lT[qt][0] + Lx[64 + 16 * qt + l16] +
                     Lx[128 + 16 * qt + l16] + Lx[192 + 16 * qt + l16];
        if (!partial) {
            #pragma unroll
            for (int qt = 0; qt < 4; ++qt) {
                const float inv = 1.0f / ls[qt];
                const size_t rowoff = (size_t)(q0 + 16 * qt + l16) * DM + h * HD;
                #pragma unroll
                for (int dt = 0; dt < 4; ++dt) {
                    ushort4 u;
                    u.x = f2b(oT[dt][qt][0] * inv);
                    u.y = f2b(oT[dt][qt][1] * inv);
                    u.z = f2b(oT[dt][qt][2] * inv);
                    u.w = f2b(oT[dt][qt][3] * inv);
                    *(ushort4*)&O[rowoff + 16 * dt + 4 * quad] = u;
                }
            }
        } else {
            // Partials in [q][d] layout matching the C-fragment:
            // oT[dt][qt][r] = O[q=16qt+l16][d=16dt+4quad+r].
            float* P = Part + (size_t)(((i - 32) * 12 + h) * 2 + pslice) * 4160;
            #pragma unroll
            for (int dt = 0; dt < 4; ++dt)
                #pragma unroll
                for (int qt = 0; qt < 4; ++qt)
                    *(f32x4*)&P[(16 * qt + l16) * 64 + 16 * dt + 4 * quad] = oT[dt][qt];
            if (quad == 0) {
                #pragma unroll
                for (int qt = 0; qt < 4; ++qt)
                    P[4096 + 16 * qt + l16] = ls[qt];
            }
        }
    }
}

// ---------------------------------------------------------------------------
// K2b: combine the two key-slices for q-tiles 32..63, normalize, write O.
// Grid (384): b -> (i = 32 + b/12, h = b%12). Partials are [q][d] fp32.
// ---------------------------------------------------------------------------
__global__ __launch_bounds__(256) void reduce_attn(
    const float* __restrict__ Part, unsigned short* __restrict__ O)
{
    const int b  = blockIdx.x;
    const int i  = 32 + b / 12, h = b % 12;
    const int q0 = i * 64;
    const float* P0 = Part + (size_t)(b * 2 + 0) * 4160;
    const float* P1 = Part + (size_t)(b * 2 + 1) * 4160;
    __shared__ float linv[64];
    const int t = threadIdx.x;
    if (t < 64) linv[t] = 1.0f / (P0[4096 + t] + P1[4096 + t]);
    __syncthreads();
    for (int idx = t; idx < 4096; idx += 256) {
        const int q = idx >> 6, d = idx & 63;
        const float v = (P0[q * 64 + d] + P1[q * 64 + d]) * linv[q];
        O[(size_t)(q0 + q) * DM + h * HD + d] = f2b(v);
    }
}

// ---------------------------------------------------------------------------
// K3: output projection out = A @ Wo.T + bo (MFMA) — unchanged (verified).
// ---------------------------------------------------------------------------
__global__ __launch_bounds__(256) void proj_mfma(
    const unsigned short* __restrict__ A,
    const float* __restrict__ Wo, const unsigned short* __restrict__ Wob,
    const float* __restrict__ bo,
    float* __restrict__ out, int fast)
{
    __shared__ __align__(16) unsigned short Xs[2][4096];
    __shared__ __align__(16) unsigned short Ws[2][4096];

    const int t    = threadIdx.x;
    const int w    = t >> 6;
    const int lane = t & 63;
    const int quad = lane >> 4;
    const int l16  = lane & 15;

    const int gid = blockIdx.y * 64 + blockIdx.x;   // 0..767
    const int Wl  = (gid & 7) * 96 + (gid >> 3);    // bijective
    const int s0  = (Wl / 12) * 64;
    const int n0  = (Wl % 12) * 64;

    const int prow = t >> 3, pblk = t & 7;

    f32x4 acc[4] = {{0,0,0,0},{0,0,0,0},{0,0,0,0},{0,0,0,0}};

    bf16x8 ar0, ar1, wr0, wr1;
    ar0 = *(const bf16x8*)&A[(size_t)(s0 + prow) * DM + pblk * 8];
    ar1 = *(const bf16x8*)&A[(size_t)(s0 + prow + 32) * DM + pblk * 8];
    *(bf16x8*)&Xs[0][SWZ(prow, pblk)]      = ar0;
    *(bf16x8*)&Xs[0][SWZ(prow + 32, pblk)] = ar1;
    if (fast) {
        wr0 = *(const bf16x8*)&Wob[(size_t)(n0 + prow) * DM + pblk * 8];
        wr1 = *(const bf16x8*)&Wob[(size_t)(n0 + prow + 32) * DM + pblk * 8];
        *(bf16x8*)&Ws[0][SWZ(prow, pblk)]      = wr0;
        *(bf16x8*)&Ws[0][SWZ(prow + 32, pblk)] = wr1;
    } else {
        for (int e = t; e < 1024; e += 256) {
            const int row = e >> 4, c4 = e & 15;
            const float4 wv = *(const float4*)&Wo[(size_t)(n0 + row) * DM + c4 * 4];
            s16x4 pw; pw.x = (short)f2b(wv.x); pw.y = (short)f2b(wv.y);
            pw.z = (short)f2b(wv.z); pw.w = (short)f2b(wv.w);
            *(s16x4*)&Ws[0][SWZ(row, c4 >> 1) + (c4 & 1) * 4] = pw;
        }
    }
    __syncthreads();

    for (int kt = 0; kt < 12; ++kt) {
        const unsigned short* Xb  = Xs[kt & 1];
        const unsigned short* Wbt = Ws[kt & 1];
        if (kt < 11) {
            const int k0 = (kt + 1) * 64;
            ar0 = *(const bf16x8*)&A[(size_t)(s0 + prow) * DM + k0 + pblk * 8];
            ar1 = *(const bf16x8*)&A[(size_t)(s0 + prow + 32) * DM + k0 + pblk * 8];
            if (fast) {
                wr0 = *(const bf16x8*)&Wob[(size_t)(n0 + prow) * DM + k0 + pblk * 8];
                wr1 = *(const bf16x8*)&Wob[(size_t)(n0 + prow + 32) * DM + k0 + pblk * 8];
            }
        }
        const bf16x8 a0 = *(const bf16x8*)&Xb[SWZ(16 * w + l16, quad)];
        const bf16x8 a1 = *(const bf16x8*)&Xb[SWZ(16 * w + l16, 4 + quad)];
        #pragma unroll
        for (int nt = 0; nt < 4; ++nt) {
            const bf16x8 b0 = *(const bf16x8*)&Wbt[SWZ(16 * nt + l16, quad)];
            const bf16x8 b1 = *(const bf16x8*)&Wbt[SWZ(16 * nt + l16, 4 + quad)];
            acc[nt] = MFMA(a0, b0, acc[nt]);
            acc[nt] = MFMA(a1, b1, acc[nt]);
        }
        if (kt < 11) {
            const int nb = (kt + 1) & 1;
            *(bf16x8*)&Xs[nb][SWZ(prow, pblk)]      = ar0;
            *(bf16x8*)&Xs[nb][SWZ(prow + 32, pblk)] = ar1;
            if (fast) {
                *(bf16x8*)&Ws[nb][SWZ(prow, pblk)]      = wr0;
                *(bf16x8*)&Ws[nb][SWZ(prow + 32, pblk)] = wr1;
            } else {
                const int k0 = (kt + 1) * 64;
                for (int e = t; e < 1024; e += 256) {
                    const int row = e >> 4, c4 = e & 15;
                    const float4 wv = *(const float4*)&Wo[(size_t)(n0 + row) * DM + k0 + c4 * 4];
                    s16x4 pw; pw.x = (short)f2b(wv.x); pw.y = (short)f2b(wv.y);
                    pw.z = (short)f2b(wv.z); pw.w = (short)f2b(wv.w);
                    *(s16x4*)&Ws[nb][SWZ(row, c4 >> 1) + (c4 & 1) * 4] = pw;
                }
            }
        }
        __syncthreads();
    }

    #pragma unroll
    for (int nt = 0; nt < 4; ++nt)
        #pragma unroll
        for (int r = 0; r < 4; ++r) {
            const int srow = s0 + 16 * w + quad * 4 + r;
            const int n    = n0 + nt * 16 + l16;
            out[(size_t)srow * DM + n] = acc[nt][r] + bo[n];
        }
}

// ---------------------------------------------------------------------------
extern "C" void kernel_launch(void* const* d_in, const int* in_sizes, int n_in,
                              void* d_out, int out_size, void* d_ws, size_t ws_size,
                              hipStream_t stream) {
    const float* x  = (const float*)d_in[0];
    const float* Wq = (const float*)d_in[2];
    const float* Wk = (const float*)d_in[3];
    const float* Wv = (const float*)d_in[4];
    const float* Wo = (const float*)d_in[5];
    const float* bo = (const float*)d_in[6];
    float* out = (float*)d_out;

    unsigned short* U  = (unsigned short*)d_ws;
    unsigned short* Qw = U;
    unsigned short* Kw = U + PER;
    unsigned short* Vw = U + 2 * PER;    // transposed [h][64][seq], interleaved
    unsigned short* Ow = U + 3 * PER;    // [4096][768]
    unsigned short* xb  = U + 4 * PER;
    unsigned short* Wqb = xb + XN;
    unsigned short* Wkb = Wqb + WN;
    unsigned short* Wvb = Wkb + WN;
    unsigned short* Wob = Wvb + WN;
    float2* rope = (float2*)(Wob + WN);  // [4096][32]
    float*  part = (float*)(rope + 4096 * 32);   // [384][2][4160] fp32
    const size_t need  = (char*)part - (char*)d_ws;
    const size_t need2 = need + (size_t)384 * 2 * 4160 * 4;
    const int fast  = (ws_size >= need)  ? 1 : 0;
    const int split = (ws_size >= need2) ? 1 : 0;

    if (fast)
        prep_kernel<<<1024, 256, 0, stream>>>(x, Wq, Wk, Wv, Wo, xb, rope);
    qkv_mfma<<<dim3(64, 12), 256, 0, stream>>>(
        x, xb, Wq, Wk, Wv, Wqb, Wkb, Wvb, rope, Qw, Kw, Vw, fast);
    if (split) {
        attn_mfma<<<dim3(96, NH), 256, 0, stream>>>(Qw, Kw, Vw, Ow, part);
        reduce_attn<<<dim3(384), 256, 0, stream>>>(part, Ow);
    } else {
        attn_mfma<<<dim3(64, 12), 256, 0, stream>>>(Qw, Kw, Vw, Ow, part);
    }
    proj_mfma<<<dim3(SEQ / 64, DM / 64), 256, 0, stream>>>(Ow, Wo, Wob, bo, out, fast);
}

// Round 15
// 231.016 us; speedup vs baseline: 1.0226x; 1.0226x over previous
//
#include <hip/hip_runtime.h>
#include <hip/hip_bf16.h>
#include <math.h>

#define SEQ 4096
#define DM  768
#define NH  12
#define HD  64
#define PER ((size_t)NH * SEQ * HD)       // 3,145,728
#define XN  ((size_t)SEQ * DM)
#define WN  ((size_t)DM * DM)

typedef __attribute__((ext_vector_type(8))) short bf16x8;   // MFMA A/B frag
typedef __attribute__((ext_vector_type(4))) short s16x4;
typedef __attribute__((ext_vector_type(4))) float f32x4;    // MFMA C/D frag

#define MFMA(a, b, c) __builtin_amdgcn_mfma_f32_16x16x32_bf16((a), (b), (c), 0, 0, 0)

#if __has_builtin(__builtin_amdgcn_exp2f)
#define EXP2(x) __builtin_amdgcn_exp2f(x)
#else
#define EXP2(x) exp2f(x)
#endif

// XOR-swizzled 64-wide bf16 LDS tile, 16B blocks (conflict-free b128).
#define SWZ(row, blk) (((row) << 6) + ((((blk) ^ ((row) & 7))) << 3))

// fast RTNE fp32->bf16 (finite values only)
__device__ __forceinline__ unsigned short f2b(float f) {
    unsigned int u = __float_as_uint(f);
    u += 0x7FFFu + ((u >> 16) & 1u);
    return (unsigned short)(u >> 16);
}

// ---------------------------------------------------------------------------
// Prep: ONE kernel converts x + 4 weights fp32->bf16 and fills the RoPE table.
// ---------------------------------------------------------------------------
__global__ __launch_bounds__(256) void prep_kernel(
    const float* __restrict__ x,  const float* __restrict__ wq,
    const float* __restrict__ wk, const float* __restrict__ wv,
    const float* __restrict__ wo,
    unsigned short* __restrict__ dstbase, float2* __restrict__ rope)
{
    const float* srcs[5] = {x, wq, wk, wv, wo};
    const size_t n4s[5]  = {XN / 4, WN / 4, WN / 4, WN / 4, WN / 4};
    unsigned short* d = dstbase;
    for (int rg = 0; rg < 5; ++rg) {
        const float4* s4 = (const float4*)srcs[rg];
        s16x4* d4 = (s16x4*)d;
        for (size_t i = (size_t)blockIdx.x * 256 + threadIdx.x; i < n4s[rg];
             i += (size_t)gridDim.x * 256) {
            const float4 v = s4[i];
            s16x4 p;
            p.x = (short)f2b(v.x); p.y = (short)f2b(v.y);
            p.z = (short)f2b(v.z); p.w = (short)f2b(v.w);
            d4[i] = p;
        }
        d += n4s[rg] * 4;
    }
    for (int g = blockIdx.x * 256 + threadIdx.x; g < 131072; g += gridDim.x * 256) {
        const int row = g >> 5, fi = g & 31;
        const float invf = expf(-(float)fi * 0.28782313662425576f);
        float sn, cs;
        sincosf((float)row * invf, &sn, &cs);
        rope[row * 32 + fi] = make_float2(cs, sn);
    }
}

// ---------------------------------------------------------------------------
// K1: QKV projection (x @ W.T, MFMA) — round-2 verified (session best).
// ---------------------------------------------------------------------------
__global__ __launch_bounds__(256) void qkv_mfma(
    const float* __restrict__ x,  const unsigned short* __restrict__ xb,
    const float* __restrict__ Wq, const float* __restrict__ Wk, const float* __restrict__ Wv,
    const unsigned short* __restrict__ Wqb, const unsigned short* __restrict__ Wkb,
    const unsigned short* __restrict__ Wvb,
    const float2* __restrict__ rope,
    unsigned short* __restrict__ Qo, unsigned short* __restrict__ Ko,
    unsigned short* __restrict__ Vo, int fast)
{
    __shared__ __align__(16) unsigned short Xs[2][4096];
    __shared__ __align__(16) unsigned short Ws[2][4096];
    __shared__ unsigned short VL[64 * 66];

    const int t    = threadIdx.x;
    const int w    = t >> 6;
    const int lane = t & 63;
    const int quad = lane >> 4;
    const int l16  = lane & 15;

    const int nt_b = blockIdx.y;
    const float* W; const unsigned short* Wb; int region;
    if (nt_b < 12)      { W = Wq; Wb = Wqb; region = 0; }
    else if (nt_b < 24) { W = Wk; Wb = Wkb; region = 1; }
    else                { W = Wv; Wb = Wvb; region = 2; }
    const int h  = nt_b % 12;
    const int s0 = blockIdx.x * 64;
    const int n0 = h * 64;

    f32x4 acc[4] = {{0,0,0,0},{0,0,0,0},{0,0,0,0},{0,0,0,0}};
    const int prow = t >> 3, pblk = t & 7;

    bf16x8 xr0, xr1, wr0, wr1;
    if (fast) {
        xr0 = *(const bf16x8*)&xb[(size_t)(s0 + prow) * DM + pblk * 8];
        xr1 = *(const bf16x8*)&xb[(size_t)(s0 + prow + 32) * DM + pblk * 8];
        wr0 = *(const bf16x8*)&Wb[(size_t)(n0 + prow) * DM + pblk * 8];
        wr1 = *(const bf16x8*)&Wb[(size_t)(n0 + prow + 32) * DM + pblk * 8];
        *(bf16x8*)&Xs[0][SWZ(prow, pblk)]      = xr0;
        *(bf16x8*)&Xs[0][SWZ(prow + 32, pblk)] = xr1;
        *(bf16x8*)&Ws[0][SWZ(prow, pblk)]      = wr0;
        *(bf16x8*)&Ws[0][SWZ(prow + 32, pblk)] = wr1;
    } else {
        for (int e = t; e < 1024; e += 256) {
            const int row = e >> 4, c4 = e & 15;
            const int off = SWZ(row, c4 >> 1) + (c4 & 1) * 4;
            const float4 xv = *(const float4*)&x[(size_t)(s0 + row) * DM + c4 * 4];
            s16x4 px; px.x = (short)f2b(xv.x); px.y = (short)f2b(xv.y);
            px.z = (short)f2b(xv.z); px.w = (short)f2b(xv.w);
            *(s16x4*)&Xs[0][off] = px;
            const float4 wv = *(const float4*)&W[(size_t)(n0 + row) * DM + c4 * 4];
            s16x4 pw; pw.x = (short)f2b(wv.x); pw.y = (short)f2b(wv.y);
            pw.z = (short)f2b(wv.z); pw.w = (short)f2b(wv.w);
            *(s16x4*)&Ws[0][off] = pw;
        }
    }
    __syncthreads();

    for (int kt = 0; kt < 12; ++kt) {
        const unsigned short* Xb  = Xs[kt & 1];
        const unsigned short* Wbt = Ws[kt & 1];
        if (fast && kt < 11) {
            const int k0 = (kt + 1) * 64;
            xr0 = *(const bf16x8*)&xb[(size_t)(s0 + prow) * DM + k0 + pblk * 8];
            xr1 = *(const bf16x8*)&xb[(size_t)(s0 + prow + 32) * DM + k0 + pblk * 8];
            wr0 = *(const bf16x8*)&Wb[(size_t)(n0 + prow) * DM + k0 + pblk * 8];
            wr1 = *(const bf16x8*)&Wb[(size_t)(n0 + prow + 32) * DM + k0 + pblk * 8];
        }
        const bf16x8 a0 = *(const bf16x8*)&Xb[SWZ(16 * w + l16, quad)];
        const bf16x8 a1 = *(const bf16x8*)&Xb[SWZ(16 * w + l16, 4 + quad)];
        #pragma unroll
        for (int nt = 0; nt < 4; ++nt) {
            const bf16x8 b0 = *(const bf16x8*)&Wbt[SWZ(16 * nt + l16, quad)];
            const bf16x8 b1 = *(const bf16x8*)&Wbt[SWZ(16 * nt + l16, 4 + quad)];
            acc[nt] = MFMA(a0, b0, acc[nt]);
            acc[nt] = MFMA(a1, b1, acc[nt]);
        }
        if (kt < 11) {
            const int nb = (kt + 1) & 1;
            if (fast) {
                *(bf16x8*)&Xs[nb][SWZ(prow, pblk)]      = xr0;
                *(bf16x8*)&Xs[nb][SWZ(prow + 32, pblk)] = xr1;
                *(bf16x8*)&Ws[nb][SWZ(prow, pblk)]      = wr0;
                *(bf16x8*)&Ws[nb][SWZ(prow + 32, pblk)] = wr1;
            } else {
                const int k0 = (kt + 1) * 64;
                for (int e = t; e < 1024; e += 256) {
                    const int row = e >> 4, c4 = e & 15;
                    const int off = SWZ(row, c4 >> 1) + (c4 & 1) * 4;
                    const float4 xv = *(const float4*)&x[(size_t)(s0 + row) * DM + k0 + c4 * 4];
                    s16x4 px; px.x = (short)f2b(xv.x); px.y = (short)f2b(xv.y);
                    px.z = (short)f2b(xv.z); px.w = (short)f2b(xv.w);
                    *(s16x4*)&Xs[nb][off] = px;
                    const float4 wv = *(const float4*)&W[(size_t)(n0 + row) * DM + k0 + c4 * 4];
                    s16x4 pw; pw.x = (short)f2b(wv.x); pw.y = (short)f2b(wv.y);
                    pw.z = (short)f2b(wv.z); pw.w = (short)f2b(wv.w);
                    *(s16x4*)&Ws[nb][off] = pw;
                }
            }
        }
        __syncthreads();
    }

    const size_t headoff = (size_t)h * SEQ * HD;
    if (region <= 1) {
        unsigned short* dst = (region == 0) ? Qo : Ko;
        const float qsc = (region == 0) ? 0.18033688011112042f : 1.0f;   // 0.125*log2e
        #pragma unroll
        for (int nt = 0; nt < 4; ++nt)
            #pragma unroll
            for (int r = 0; r < 4; ++r) {
                const int srow = s0 + 16 * w + quad * 4 + r;
                const int d  = nt * 16 + l16;
                const int fi = d >> 1;
                const float own = acc[nt][r] * qsc;
                const float oth = __shfl_xor(own, 1);
                float cs, sn;
                if (fast) {
                    const float2 t2 = rope[srow * 32 + fi];
                    cs = t2.x; sn = t2.y;
                } else {
                    const float invf = expf(-(float)fi * 0.28782313662425576f);
                    sincosf((float)srow * invf, &sn, &cs);
                }
                const float val = (d & 1) ? (oth * sn + own * cs)
                                          : (own * cs - oth * sn);
                dst[headoff + (size_t)srow * HD + ((d & 1) ? 32 : 0) + fi] = f2b(val);
            }
    } else {
        #pragma unroll
        for (int nt = 0; nt < 4; ++nt)
            #pragma unroll
            for (int r = 0; r < 4; ++r)
                VL[(nt * 16 + l16) * 66 + 16 * w + quad * 4 + r] = f2b(acc[nt][r]);
        __syncthreads();
        for (int e = t; e < 2048; e += 256) {
            const int d = e >> 5, sp = e & 31;
            const unsigned int v = (unsigned int)VL[d * 66 + 2 * sp] |
                                   ((unsigned int)VL[d * 66 + 2 * sp + 1] << 16);
            *(unsigned int*)&Vo[headoff + (size_t)d * SEQ + s0 + 2 * sp] = v;
        }
    }
}

// ---------------------------------------------------------------------------
// K2: causal flash attention — round-2 verified (session best: attn 75.3µs).
// LDS staging, reg prefetch, 2 barriers/chunk, qt-major QK+exp fusion
// (MFMA(qt+1) ∥ VALU(qt) on separate pipes), XCD head-clustered remap
// (~2MB K/V working set per XCD -> L2-resident; FETCH 52->10.3MB).
// NOTE (rounds 6-9): this 64-row/4-wave/16x16-MFMA decomposition is pinned
// at ~75µs by a per-block critical-path floor — direct-load, barrier-free,
// chunk-pipelined, packed-store, and finer-sliced variants all measured
// 74.5-77.7µs. The next step-change requires the 8-warp/32x32/swapped-QK
// in-register-softmax structure (full rewrite), not issue-side tuning.
// ---------------------------------------------------------------------------
__global__ __launch_bounds__(256, 2) void attn_mfma(
    const unsigned short* __restrict__ Q,    // [h][seq][64], pre-scaled
    const unsigned short* __restrict__ K,    // [h][seq][64]
    const unsigned short* __restrict__ V,    // [h][64][seq]  (transposed)
    unsigned short* __restrict__ O,          // [4096][768]
    float* __restrict__ Part)                // [384][2][4160] fp32 partials
{
    __shared__ __align__(16) unsigned char SM[53248];
    unsigned short* Kst = (unsigned short*)SM;             // 128x64 SWZ, 16KB
    unsigned short* Vt  = (unsigned short*)(SM + 16384);   // 64x128 SWZ16, 16KB
    unsigned short* Ps  = (unsigned short*)(SM + 32768);   // 4 strips 64x40, 20KB
    float* ACC  = (float*)SM;
    float* ACC2 = (float*)(SM + 32768);
    float* Lx   = (float*)(SM + 51200);

    // ---- XCD-clustered (head-major) block remap ----
    int h, xx;
    if (gridDim.x == 96) {
        const int gid = blockIdx.y * 96 + blockIdx.x;      // 0..1151
        const int Wl  = (gid & 7) * 144 + (gid >> 3);      // bijective
        h  = Wl / 96;
        xx = Wl - h * 96;
    } else {
        const int gid = blockIdx.y * 64 + blockIdx.x;      // 0..767
        const int Wl  = (gid & 7) * 96 + (gid >> 3);
        h  = Wl >> 6;
        xx = Wl & 63;
    }

    int i, kstart, nch, domask, partial, pslice;
    if (gridDim.x == 96) {
        if (xx < 64) {
            i = 63 - xx; kstart = 0;
            const int full = ((i * 64 + 63) >> 7) + 1;
            nch = full < 16 ? full : 16;
            domask  = (i <= 31);
            partial = (i >= 32); pslice = 0;
        } else {
            i = 127 - xx; kstart = 2048;
            nch = ((i * 64 + 63 - 2048) >> 7) + 1;
            domask = 1; partial = 1; pslice = 1;
        }
    } else {
        i = 63 - xx; kstart = 0;
        nch = ((i * 64 + 63) >> 7) + 1;
        domask = 1; partial = 0; pslice = 0;
    }
    const int q0 = i * 64;

    const int t    = threadIdx.x;
    const int w    = t >> 6;
    const int lane = t & 63;
    const int quad = lane >> 4;
    const int l16  = lane & 15;
    const size_t headoff = (size_t)h * SEQ * HD;

    // ---- stage Q (SWZ64) into Kst, read A-frags for all 64 rows ----
    for (int e = t; e < 512; e += 256) {
        const int row = e >> 3, bp = e & 7, blk = bp ^ (row & 7);
        *(bf16x8*)&Kst[row * 64 + bp * 8] =
            *(const bf16x8*)&Q[headoff + (size_t)(q0 + row) * HD + blk * 8];
    }
    __syncthreads();
    bf16x8 aQ[4][2];
    #pragma unroll
    for (int qt = 0; qt < 4; ++qt)
        #pragma unroll
        for (int hh = 0; hh < 2; ++hh)
            aQ[qt][hh] = *(const bf16x8*)&Kst[SWZ(16 * qt + l16, 4 * hh + quad)];
    __syncthreads();

    // ---- stage chunk 0 (keys kstart..kstart+127) ----
    bf16x8 kreg[4], vreg[4];
    #pragma unroll
    for (int ii = 0; ii < 4; ++ii) {
        const int e = t + ii * 256, row = e >> 3, bp = e & 7, blk = bp ^ (row & 7);
        kreg[ii] = *(const bf16x8*)&K[headoff + (size_t)(kstart + row) * HD + blk * 8];
    }
    #pragma unroll
    for (int ii = 0; ii < 4; ++ii) {
        const int e = t + ii * 256, row = e >> 4, bp = e & 15, blk = bp ^ (row & 15);
        vreg[ii] = *(const bf16x8*)&V[headoff + (size_t)row * SEQ + kstart + blk * 8];
    }
    #pragma unroll
    for (int ii = 0; ii < 4; ++ii) {
        const int e = t + ii * 256, row = e >> 3, bp = e & 7;
        *(bf16x8*)&Kst[row * 64 + bp * 8] = kreg[ii];
    }
    #pragma unroll
    for (int ii = 0; ii < 4; ++ii) {
        const int e = t + ii * 256, row = e >> 4, bp = e & 15;
        *(bf16x8*)&Vt[row * 128 + bp * 8] = vreg[ii];
    }
    __syncthreads();

    bf16x8 ones;
    #pragma unroll
    for (int ii = 0; ii < 8; ++ii) ones[ii] = (short)0x3F80;

    f32x4 oT[4][4];
    #pragma unroll
    for (int dt = 0; dt < 4; ++dt)
        #pragma unroll
        for (int qt = 0; qt < 4; ++qt) oT[dt][qt] = (f32x4){0,0,0,0};
    f32x4 lT[4] = {{0,0,0,0},{0,0,0,0},{0,0,0,0},{0,0,0,0}};

    unsigned short* usp = Ps + w * 2560;

    for (int c = 0; c < nch; ++c) {
        const int k0 = kstart + c * 128;
        const int last = (c == nch - 1);

        // ---- operand preloads from LDS (independent of P strips) ----
        bf16x8 bK[2][2];
        #pragma unroll
        for (int kt = 0; kt < 2; ++kt)
            #pragma unroll
            for (int hh = 0; hh < 2; ++hh)
                bK[kt][hh] = *(const bf16x8*)
                    &Kst[SWZ(32 * w + 16 * kt + l16, 4 * hh + quad)];
        bf16x8 aV[4];
        #pragma unroll
        for (int dt = 0; dt < 4; ++dt) {
            const int row = 16 * dt + l16;
            aV[dt] = *(const bf16x8*)&Vt[row * 128 + (((4 * w + quad) ^ (row & 15)) << 3)];
        }

        // ---- global prefetch of next chunk (full PV phase + barrier of cover)
        if (c + 1 < nch) {
            const int kn = k0 + 128;
            #pragma unroll
            for (int ii = 0; ii < 4; ++ii) {
                const int e = t + ii * 256, row = e >> 3, bp = e & 7, blk = bp ^ (row & 7);
                kreg[ii] = *(const bf16x8*)&K[headoff + (size_t)(kn + row) * HD + blk * 8];
            }
            #pragma unroll
            for (int ii = 0; ii < 4; ++ii) {
                const int e = t + ii * 256, row = e >> 4, bp = e & 15, blk = bp ^ (row & 15);
                vreg[ii] = *(const bf16x8*)&V[headoff + (size_t)row * SEQ + kn + blk * 8];
            }
        }

        // ---- qt-major QK + mask + exp2 + P store (MFMA(qt+1) ∥ VALU(qt)) ----
        #pragma unroll
        for (int qt = 0; qt < 4; ++qt) {
            f32x4 s0 = (f32x4){0,0,0,0}, s1 = (f32x4){0,0,0,0};
            #pragma unroll
            for (int hh = 0; hh < 2; ++hh) {
                s0 = MFMA(aQ[qt][hh], bK[0][hh], s0);
                s1 = MFMA(aQ[qt][hh], bK[1][hh], s1);
            }
            if (domask && last) {
                const int key0 = k0 + 32 * w + l16;
                #pragma unroll
                for (int r = 0; r < 4; ++r) {
                    const int qrow = q0 + 16 * qt + 4 * quad + r;
                    if (key0 > qrow)      s0[r] = -1e30f;
                    if (key0 + 16 > qrow) s1[r] = -1e30f;
                }
            }
            #pragma unroll
            for (int r = 0; r < 4; ++r) {
                const int row = (16 * qt + 4 * quad + r) * 40;
                usp[row + l16]      = f2b(EXP2(s0[r]));
                usp[row + 16 + l16] = f2b(EXP2(s1[r]));
            }
        }

        asm volatile("s_waitcnt lgkmcnt(0)" ::: "memory");

        // ---- PV + row-sum ----
        __builtin_amdgcn_s_setprio(1);
        #pragma unroll
        for (int qt = 0; qt < 4; ++qt) {
            const bf16x8 bP = *(const bf16x8*)&usp[(16 * qt + l16) * 40 + quad * 8];
            lT[qt] = MFMA(ones, bP, lT[qt]);
            #pragma unroll
            for (int dt = 0; dt < 4; ++dt)
                oT[dt][qt] = MFMA(aV[dt], bP, oT[dt][qt]);
        }
        __builtin_amdgcn_s_setprio(0);

        __syncthreads();
        if (c + 1 < nch) {
            #pragma unroll
            for (int ii = 0; ii < 4; ++ii) {
                const int e = t + ii * 256, row = e >> 3, bp = e & 7;
                *(bf16x8*)&Kst[row * 64 + bp * 8] = kreg[ii];
            }
            #pragma unroll
            for (int ii = 0; ii < 4; ++ii) {
                const int e = t + ii * 256, row = e >> 4, bp = e & 15;
                *(bf16x8*)&Vt[row * 128 + bp * 8] = vreg[ii];
            }
        }
        __syncthreads();
    }

    // ---- cross-wave reduction of O^T and l ----
    if (w != 0 && quad == 0) {
        #pragma unroll
        for (int qt = 0; qt < 4; ++qt)
            Lx[w * 64 + 16 * qt + l16] = lT[qt][0];
    }
    if (w == 1) {
        #pragma unroll
        for (int dt = 0; dt < 4; ++dt)
            #pragma unroll
            for (int qt = 0; qt < 4; ++qt)
                *(f32x4*)&ACC[(16 * qt + l16) * 72 + 16 * dt + 4 * quad] = oT[dt][qt];
    }
    __syncthreads();
    if (w == 0) {
        #pragma unroll
        for (int dt = 0; dt < 4; ++dt)
            #pragma unroll
            for (int qt = 0; qt < 4; ++qt)
                oT[dt][qt] += *(const f32x4*)&ACC[(16 * qt + l16) * 72 + 16 * dt + 4 * quad];
    }
    if (w == 2) {
        #pragma unroll
        for (int dt = 0; dt < 4; ++dt)
            #pragma unroll
            for (int qt = 0; qt < 4; ++qt)
                *(f32x4*)&ACC2[(16 * qt + l16) * 72 + 16 * dt + 4 * quad] = oT[dt][qt];
    }
    __syncthreads();
    if (w == 0) {
        #pragma unroll
        for (int dt = 0; dt < 4; ++dt)
            #pragma unroll
            for (int qt = 0; qt < 4; ++qt)
                oT[dt][qt] += *(const f32x4*)&ACC2[(16 * qt + l16) * 72 + 16 * dt + 4 * quad];
    }
    if (w == 3) {
        #pragma unroll
        for (int dt = 0; dt < 4; ++dt)
            #pragma unroll
            for (int qt = 0; qt < 4; ++qt)
                *(f32x4*)&ACC[(16 * qt + l16) * 72 + 16 * dt + 4 * quad] = oT[dt][qt];
    }
    __syncthreads();
    if (w == 0) {
        float ls[4];
        #pragma unroll
        for (int qt = 0; qt < 4; ++qt) {
            #pragma unroll
            for (int dt = 0; dt < 4; ++dt)
                oT[dt][qt] += *(const f32x4*)&ACC[(16 * qt + l16) * 72 + 16 * dt + 4 * quad];
            ls[qt] = lT[qt][0] + Lx[64 + 16 * qt + l16] +
                     Lx[128 + 16 * qt + l16] + Lx[192 + 16 * qt + l16];
        }
        if (!partial) {
            #pragma unroll
            for (int qt = 0; qt < 4; ++qt) {
                const float inv = 1.0f / ls[qt];
                const size_t rowoff = (size_t)(q0 + 16 * qt + l16) * DM + h * HD;
                #pragma unroll
                for (int dt = 0; dt < 4; ++dt) {
                    ushort4 u;
                    u.x = f2b(oT[dt][qt][0] * inv);
                    u.y = f2b(oT[dt][qt][1] * inv);
                    u.z = f2b(oT[dt][qt][2] * inv);
                    u.w = f2b(oT[dt][qt][3] * inv);
                    *(ushort4*)&O[rowoff + 16 * dt + 4 * quad] = u;
                }
            }
        } else {
            // Partials in [q][d] layout matching the C-fragment:
            // oT[dt][qt][r] = O[q=16qt+l16][d=16dt+4quad+r].
            float* P = Part + (size_t)(((i - 32) * 12 + h) * 2 + pslice) * 4160;
            #pragma unroll
            for (int dt = 0; dt < 4; ++dt)
                #pragma unroll
                for (int qt = 0; qt < 4; ++qt)
                    *(f32x4*)&P[(16 * qt + l16) * 64 + 16 * dt + 4 * quad] = oT[dt][qt];
            if (quad == 0) {
                #pragma unroll
                for (int qt = 0; qt < 4; ++qt)
                    P[4096 + 16 * qt + l16] = ls[qt];
            }
        }
    }
}

// ---------------------------------------------------------------------------
// K2b: combine the two key-slices for q-tiles 32..63, normalize, write O.
// Grid (384): b -> (i = 32 + b/12, h = b%12). Partials are [q][d] fp32.
// ---------------------------------------------------------------------------
__global__ __launch_bounds__(256) void reduce_attn(
    const float* __restrict__ Part, unsigned short* __restrict__ O)
{
    const int b  = blockIdx.x;
    const int i  = 32 + b / 12, h = b % 12;
    const int q0 = i * 64;
    const float* P0 = Part + (size_t)(b * 2 + 0) * 4160;
    const float* P1 = Part + (size_t)(b * 2 + 1) * 4160;
    __shared__ float linv[64];
    const int t = threadIdx.x;
    if (t < 64) linv[t] = 1.0f / (P0[4096 + t] + P1[4096 + t]);
    __syncthreads();
    for (int idx = t; idx < 4096; idx += 256) {
        const int q = idx >> 6, d = idx & 63;
        const float v = (P0[q * 64 + d] + P1[q * 64 + d]) * linv[q];
        O[(size_t)(q0 + q) * DM + h * HD + d] = f2b(v);
    }
}

// ---------------------------------------------------------------------------
// K3: output projection out = A @ Wo.T + bo (MFMA) — round-2 verified.
// ---------------------------------------------------------------------------
__global__ __launch_bounds__(256) void proj_mfma(
    const unsigned short* __restrict__ A,
    const float* __restrict__ Wo, const unsigned short* __restrict__ Wob,
    const float* __restrict__ bo,
    float* __restrict__ out, int fast)
{
    __shared__ __align__(16) unsigned short Xs[2][4096];
    __shared__ __align__(16) unsigned short Ws[2][4096];

    const int t    = threadIdx.x;
    const int w    = t >> 6;
    const int lane = t & 63;
    const int quad = lane >> 4;
    const int l16  = lane & 15;
    const int s0 = blockIdx.x * 64;
    const int n0 = blockIdx.y * 64;
    const int prow = t >> 3, pblk = t & 7;

    f32x4 acc[4] = {{0,0,0,0},{0,0,0,0},{0,0,0,0},{0,0,0,0}};

    bf16x8 ar0, ar1, wr0, wr1;
    ar0 = *(const bf16x8*)&A[(size_t)(s0 + prow) * DM + pblk * 8];
    ar1 = *(const bf16x8*)&A[(size_t)(s0 + prow + 32) * DM + pblk * 8];
    *(bf16x8*)&Xs[0][SWZ(prow, pblk)]      = ar0;
    *(bf16x8*)&Xs[0][SWZ(prow + 32, pblk)] = ar1;
    if (fast) {
        wr0 = *(const bf16x8*)&Wob[(size_t)(n0 + prow) * DM + pblk * 8];
        wr1 = *(const bf16x8*)&Wob[(size_t)(n0 + prow + 32) * DM + pblk * 8];
        *(bf16x8*)&Ws[0][SWZ(prow, pblk)]      = wr0;
        *(bf16x8*)&Ws[0][SWZ(prow + 32, pblk)] = wr1;
    } else {
        for (int e = t; e < 1024; e += 256) {
            const int row = e >> 4, c4 = e & 15;
            const float4 wv = *(const float4*)&Wo[(size_t)(n0 + row) * DM + c4 * 4];
            s16x4 pw; pw.x = (short)f2b(wv.x); pw.y = (short)f2b(wv.y);
            pw.z = (short)f2b(wv.z); pw.w = (short)f2b(wv.w);
            *(s16x4*)&Ws[0][SWZ(row, c4 >> 1) + (c4 & 1) * 4] = pw;
        }
    }
    __syncthreads();

    for (int kt = 0; kt < 12; ++kt) {
        const unsigned short* Xb  = Xs[kt & 1];
        const unsigned short* Wbt = Ws[kt & 1];
        if (kt < 11) {
            const int k0 = (kt + 1) * 64;
            ar0 = *(const bf16x8*)&A[(size_t)(s0 + prow) * DM + k0 + pblk * 8];
            ar1 = *(const bf16x8*)&A[(size_t)(s0 + prow + 32) * DM + k0 + pblk * 8];
            if (fast) {
                wr0 = *(const bf16x8*)&Wob[(size_t)(n0 + prow) * DM + k0 + pblk * 8];
                wr1 = *(const bf16x8*)&Wob[(size_t)(n0 + prow + 32) * DM + k0 + pblk * 8];
            }
        }
        const bf16x8 a0 = *(const bf16x8*)&Xb[SWZ(16 * w + l16, quad)];
        const bf16x8 a1 = *(const bf16x8*)&Xb[SWZ(16 * w + l16, 4 + quad)];
        #pragma unroll
        for (int nt = 0; nt < 4; ++nt) {
            const bf16x8 b0 = *(const bf16x8*)&Wbt[SWZ(16 * nt + l16, quad)];
            const bf16x8 b1 = *(const bf16x8*)&Wbt[SWZ(16 * nt + l16, 4 + quad)];
            acc[nt] = MFMA(a0, b0, acc[nt]);
            acc[nt] = MFMA(a1, b1, acc[nt]);
        }
        if (kt < 11) {
            const int nb = (kt + 1) & 1;
            *(bf16x8*)&Xs[nb][SWZ(prow, pblk)]      = ar0;
            *(bf16x8*)&Xs[nb][SWZ(prow + 32, pblk)] = ar1;
            if (fast) {
                *(bf16x8*)&Ws[nb][SWZ(prow, pblk)]      = wr0;
                *(bf16x8*)&Ws[nb][SWZ(prow + 32, pblk)] = wr1;
            } else {
                const int k0 = (kt + 1) * 64;
                for (int e = t; e < 1024; e += 256) {
                    const int row = e >> 4, c4 = e & 15;
                    const float4 wv = *(const float4*)&Wo[(size_t)(n0 + row) * DM + k0 + c4 * 4];
                    s16x4 pw; pw.x = (short)f2b(wv.x); pw.y = (short)f2b(wv.y);
                    pw.z = (short)f2b(wv.z); pw.w = (short)f2b(wv.w);
                    *(s16x4*)&Ws[nb][SWZ(row, c4 >> 1) + (c4 & 1) * 4] = pw;
                }
            }
        }
        __syncthreads();
    }

    #pragma unroll
    for (int nt = 0; nt < 4; ++nt)
        #pragma unroll
        for (int r = 0; r < 4; ++r) {
            const int srow = s0 + 16 * w + quad * 4 + r;
            const int n    = n0 + nt * 16 + l16;
            out[(size_t)srow * DM + n] = acc[nt][r] + bo[n];
        }
}

// ---------------------------------------------------------------------------
extern "C" void kernel_launch(void* const* d_in, const int* in_sizes, int n_in,
                              void* d_out, int out_size, void* d_ws, size_t ws_size,
                              hipStream_t stream) {
    const float* x  = (const float*)d_in[0];
    const float* Wq = (const float*)d_in[2];
    const float* Wk = (const float*)d_in[3];
    const float* Wv = (const float*)d_in[4];
    const float* Wo = (const float*)d_in[5];
    const float* bo = (const float*)d_in[6];
    float* out = (float*)d_out;

    unsigned short* U  = (unsigned short*)d_ws;
    unsigned short* Qw = U;
    unsigned short* Kw = U + PER;
    unsigned short* Vw = U + 2 * PER;    // transposed [h][64][seq]
    unsigned short* Ow = U + 3 * PER;    // [4096][768]
    unsigned short* xb  = U + 4 * PER;
    unsigned short* Wqb = xb + XN;
    unsigned short* Wkb = Wqb + WN;
    unsigned short* Wvb = Wkb + WN;
    unsigned short* Wob = Wvb + WN;
    float2* rope = (float2*)(Wob + WN);  // [4096][32]
    float*  part = (float*)(rope + 4096 * 32);   // [384][2][4160] fp32
    const size_t need  = (char*)part - (char*)d_ws;
    const size_t need2 = need + (size_t)384 * 2 * 4160 * 4;
    const int fast  = (ws_size >= need)  ? 1 : 0;
    const int split = (ws_size >= need2) ? 1 : 0;

    if (fast)
        prep_kernel<<<1024, 256, 0, stream>>>(x, Wq, Wk, Wv, Wo, xb, rope);
    qkv_mfma<<<dim3(SEQ / 64, 36), 256, 0, stream>>>(
        x, xb, Wq, Wk, Wv, Wqb, Wkb, Wvb, rope, Qw, Kw, Vw, fast);
    if (split) {
        attn_mfma<<<dim3(96, NH), 256, 0, stream>>>(Qw, Kw, Vw, Ow, part);
        reduce_attn<<<dim3(384), 256, 0, stream>>>(part, Ow);
    } else {
        attn_mfma<<<dim3(64, NH), 256, 0, stream>>>(Qw, Kw, Vw, Ow, part);
    }
    proj_mfma<<<dim3(SEQ / 64, DM / 64), 256, 0, stream>>>(Ow, Wo, Wob, bo, out, fast);
}